// Round 1
// 281.162 us; speedup vs baseline: 1.1278x; 1.1278x over previous
//
#include <hip/hip_runtime.h>
#include <math.h>

#define NTHR 1024
#define CAP 4096
#define BINS 4096
#define SMALL 1024
#define GUARD 16u

#define RMAX_F 0.9999999403953552f
#define RMAX_LOG_F -5.960464477539063e-08f
#define NEG_BIG -3.0e38f

__device__ __forceinline__ unsigned keyOf(float v) {
    unsigned b = __float_as_uint(v);
    return (b & 0x80000000u) ? ~b : (b | 0x80000000u);
}
__device__ __forceinline__ float valOfKey(unsigned k) {
    unsigned b = (k & 0x80000000u) ? (k ^ 0x80000000u) : ~k;
    return __uint_as_float(b);
}
__device__ __forceinline__ unsigned long long shflXor64(unsigned long long v, int m) {
    int lo = __shfl_xor((int)(unsigned)v, m);
    int hi = __shfl_xor((int)(unsigned)(v >> 32), m);
    return ((unsigned long long)(unsigned)hi << 32) | (unsigned)lo;
}

// One block per row, 1024 threads. Latency/serialization-bound -> this revision:
//  P1: 12-bit histogram (4x-batched loads); selection via wave-shfl integer
//      suffix scan (2 barriers, was 20); rare global 8-bit refine fallback.
//  P2: compaction; predicate = single float compare (monotone-equal to key
//      compare); 4x-batched loads; ballot-aggregated atomics.
//  P2.5: if ncand > 1024: in-LDS exact-kth-key refine (integer histograms over
//      candidates, 8+8+4 bits) + recompact with 16-ulp guard (post-division
//      v-ties span <= 2 key-ulps). Refined set == prefix of old sorted order.
//  P3: register/shfl hybrid bitonic, P=1024 fixed, 1 elem/thread: 45/55 passes
//      are barrier-free shfl_xor; 10 LDS passes. Identical network/output.
//      Old LDS bitonic kept as fallback for pathological nc2 > 1024.
//  P4: numerics byte-identical to previous version (sfx tree scan verbatim);
//      s_amax/s_nkeep/s_rank wave-reduced (16 atomics vs ~1k same-address).
//  P5: parallel top-K emission (slot = kept-before-run + in-run idx rank),
//      provably identical to the serial run walk; serial filler kept.
__global__ __launch_bounds__(NTHR) void sampler_kernel(
    const float* __restrict__ logits,
    const float* __restrict__ temperature,
    const int* __restrict__ top_kv,
    const float* __restrict__ top_pv,
    const float* __restrict__ gumbel,
    float* __restrict__ out,
    int B, int V, int K)
{
    const int r = blockIdx.x;
    const int tid = threadIdx.x;
    const int lane = tid & 63;
    const int wid = tid >> 6;

    __shared__ unsigned long long cand[CAP];      // 32 KB; aliased as hist in P1
    __shared__ unsigned long long cand2[SMALL];   // 8 KB refine target
    __shared__ unsigned refHist[512];             // 2 KB refine histogram
    __shared__ int wtotI[16];
    __shared__ float varr[1024];
    __shared__ float Earr[1024];
    __shared__ float sfx[1024];
    __shared__ unsigned char flagArr[1024];
    __shared__ unsigned bitmap[64];
    __shared__ unsigned s_prefix;
    __shared__ int s_cntgt, s_total, s_lvl;
    __shared__ int s_ncand, s_nc2, s_nkeep, s_rank, s_g0, s_g1;
    __shared__ unsigned long long s_amax;
    __shared__ float s_vs;

    unsigned* hist = (unsigned*)cand;             // [BINS*2] (2 privatized copies)

    const float* row = logits + (long long)r * V;
    const float* urow = gumbel + (long long)r * V;

    float traw = temperature[r];
    bool greedy = traw < 1e-5f;
    float t = greedy ? 1.0f : traw;               // ref: temp<eps -> divide by 1.0
    int k = top_kv[r];
    if (k < 1) k = 1;
    if (k > V) k = V;
    float p = top_pv[r];

    const float4* row4 = (const float4*)row;
    const int V4 = V >> 2;
    const int Vt = V4 << 2;
    const unsigned cpy = tid & 1u;

    // ---------------- Phase 1: 12-bit histogram (batched loads) ----------------
    for (int i = tid; i < BINS * 2; i += NTHR) hist[i] = 0;
    __syncthreads();
#define H4(v4) do { \
        atomicAdd(&hist[((keyOf((v4).x) >> 20) << 1) | cpy], 1u); \
        atomicAdd(&hist[((keyOf((v4).y) >> 20) << 1) | cpy], 1u); \
        atomicAdd(&hist[((keyOf((v4).z) >> 20) << 1) | cpy], 1u); \
        atomicAdd(&hist[((keyOf((v4).w) >> 20) << 1) | cpy], 1u); \
    } while (0)
    {
        int i = tid;
        for (; i + 3 * NTHR < V4; i += 4 * NTHR) {
            float4 a = row4[i];
            float4 b = row4[i + NTHR];
            float4 c = row4[i + 2 * NTHR];
            float4 d = row4[i + 3 * NTHR];
            H4(a); H4(b); H4(c); H4(d);
        }
        for (; i < V4; i += NTHR) {
            float4 a = row4[i];
            H4(a);
        }
        for (int ii = Vt + tid; ii < V; ii += NTHR)
            atomicAdd(&hist[((keyOf(row[ii]) >> 20) << 1) | cpy], 1u);
    }
    __syncthreads();
    // selection: per-thread 4-bin chunk sums -> wave shfl suffix scan (exact int)
    {
        int base = tid << 2;
        int cs = 0;
        #pragma unroll
        for (int j = 0; j < 4; ++j)
            cs += (int)(hist[(base + j) * 2] + hist[(base + j) * 2 + 1]);
        int vv = cs;
        #pragma unroll
        for (int d = 1; d < 64; d <<= 1) {
            int o = __shfl_down(vv, d);
            if (lane + d < 64) vv += o;
        }
        if (lane == 0) wtotI[wid] = vv;
        __syncthreads();
        int off = 0;
        for (int w = wid + 1; w < 16; ++w) off += wtotI[w];
        int mine = vv + off;                      // inclusive suffix at chunk tid
        int above = mine - cs;
        if (mine >= k && above < k) {             // exactly one thread
            int run = above;
            for (int b = base + 3; b >= base; --b) {
                int mb = (int)(hist[b * 2] + hist[b * 2 + 1]);
                if (run + mb >= k) {
                    s_prefix = (unsigned)b; s_cntgt = run; s_total = run + mb; s_lvl = 0;
                    break;
                }
                run += mb;
            }
        }
    }
    // rare global refine fallback (cut bucket too fat for CAP)
    for (int level = 1; level <= 2; ++level) {
        __syncthreads();
        if (s_total <= CAP) break;                // uniform (read after barrier)
        for (int i = tid; i < 512; i += NTHR) hist[i] = 0;
        __syncthreads();
        unsigned pfx = s_prefix;
        const int msh = 32 - (12 + 8 * (level - 1));
        const int bsh = msh - 8;
        for (int i = tid; i < V4; i += NTHR) {
            float4 l4 = row4[i];
            float vv[4] = { l4.x, l4.y, l4.z, l4.w };
            #pragma unroll
            for (int j = 0; j < 4; ++j) {
                unsigned key = keyOf(vv[j]);
                if ((key >> msh) == pfx)
                    atomicAdd(&hist[(((key >> bsh) & 255u) << 1) | cpy], 1u);
            }
        }
        for (int i = Vt + tid; i < V; i += NTHR) {
            unsigned key = keyOf(row[i]);
            if ((key >> msh) == pfx)
                atomicAdd(&hist[(((key >> bsh) & 255u) << 1) | cpy], 1u);
        }
        __syncthreads();
        if (tid == 0) {
            int run = s_cntgt;
            for (int b = 255; b >= 0; --b) {
                int mb = (int)(hist[b * 2] + hist[b * 2 + 1]);
                if (run + mb >= k) {
                    s_prefix = (pfx << 8) | (unsigned)b; s_cntgt = run; s_total = run + mb;
                    break;
                }
                run += mb;
            }
            s_lvl = level;
        }
    }
    __syncthreads();
    const unsigned tlo = s_prefix << (20 - 8 * s_lvl);
    const float thrF = valOfKey(tlo);             // key>=tlo  <=>  l>=thrF (monotone)
    if (tid == 0) s_ncand = 0;
    __syncthreads();

    // ---------------- Phase 2: compaction (float-cmp predicate, batched) -------
#define EMIT_CAND(val, gidx_) do { \
        bool pred = ((val) >= thrF); \
        unsigned long long mask = __ballot(pred ? 1 : 0); \
        if (mask) { \
            int leader = __ffsll(mask) - 1; \
            int cnt = __popcll(mask); \
            int bpos = 0; \
            if (lane == leader) bpos = atomicAdd(&s_ncand, cnt); \
            bpos = __shfl(bpos, leader); \
            if (pred) { \
                int pos = bpos + __popcll(mask & ((1ULL << lane) - 1ULL)); \
                if (pos < CAP) { \
                    unsigned key = keyOf(val); \
                    cand[pos] = ((unsigned long long)key << 32) | (unsigned)(~(gidx_)); \
                } \
            } \
        } \
    } while (0)
#define C4(v4, i4) do { \
        EMIT_CAND((v4).x, (unsigned)((i4) * 4 + 0)); \
        EMIT_CAND((v4).y, (unsigned)((i4) * 4 + 1)); \
        EMIT_CAND((v4).z, (unsigned)((i4) * 4 + 2)); \
        EMIT_CAND((v4).w, (unsigned)((i4) * 4 + 3)); \
    } while (0)
    {
        int i = tid;
        for (; i + 3 * NTHR < V4; i += 4 * NTHR) {
            float4 a = row4[i];
            float4 b = row4[i + NTHR];
            float4 c = row4[i + 2 * NTHR];
            float4 d = row4[i + 3 * NTHR];
            C4(a, i); C4(b, i + NTHR); C4(c, i + 2 * NTHR); C4(d, i + 3 * NTHR);
        }
        for (; i < V4; i += NTHR) {
            float4 a = row4[i];
            C4(a, i);
        }
        for (int ii = Vt + tid; ii < V; ii += NTHR) {
            float lv = row[ii];
            EMIT_CAND(lv, (unsigned)ii);
        }
    }
    __syncthreads();
    int ncand = s_ncand; if (ncand > CAP) ncand = CAP;
    if (k > ncand) k = ncand;

    // ------- Phase 2.5: in-LDS exact-kth refine + recompact (ncand > 1024) -----
    bool fromC2 = false;
    bool bigSort = false;
    if (ncand > SMALL) {
        unsigned pfx = s_prefix;
        int run = s_cntgt;                        // count strictly above cut bucket
        int bb = 20 - 8 * s_lvl;                  // unresolved low bits of kth key
        while (bb > 0) {
            int step = (bb >= 8) ? 8 : bb;
            bb -= step;
            int nbins = 1 << step;
            for (int i = tid; i < nbins * 2; i += NTHR) refHist[i] = 0;
            __syncthreads();
            for (int i = tid; i < ncand; i += NTHR) {
                unsigned key = (unsigned)(cand[i] >> 32);
                if ((key >> (bb + step)) == pfx)
                    atomicAdd(&refHist[(((key >> bb) & (unsigned)(nbins - 1)) << 1) | cpy], 1u);
            }
            __syncthreads();
            int cnt = 0;
            if (tid < 256) cnt = (tid < nbins) ? (int)(refHist[tid * 2] + refHist[tid * 2 + 1]) : 0;
            int vv = cnt;
            #pragma unroll
            for (int d = 1; d < 64; d <<= 1) {
                int o = __shfl_down(vv, d);
                if (lane + d < 64) vv += o;
            }
            if (tid < 256 && lane == 0) wtotI[wid] = vv;
            __syncthreads();
            if (tid < 256) {
                int off = 0;
                for (int w = wid + 1; w < 4; ++w) off += wtotI[w];
                int incl = vv + off;
                int abv = incl - cnt;
                int kk = k - run;
                if (incl >= kk && abv < kk) {     // exactly one bin
                    s_prefix = (pfx << step) | (unsigned)tid;
                    s_cntgt = run + abv;
                }
            }
            __syncthreads();
            pfx = s_prefix;
            run = s_cntgt;
        }
        // pfx == exact kth-largest key; keep >= kth-16ulp (v-tie guard, span<=2)
        unsigned tref = (pfx >= tlo + GUARD) ? (pfx - GUARD) : tlo;
        if (tid == 0) s_nc2 = 0;
        __syncthreads();
        for (int i = tid; i < ncand; i += NTHR) {
            unsigned long long cv = cand[i];
            bool pred = ((unsigned)(cv >> 32) >= tref);
            unsigned long long mask = __ballot(pred ? 1 : 0);
            if (mask) {
                int leader = __ffsll(mask) - 1;
                int cnt2 = __popcll(mask);
                int bpos = 0;
                if (lane == leader) bpos = atomicAdd(&s_nc2, cnt2);
                bpos = __shfl(bpos, leader);
                if (pred) {
                    int pos = bpos + __popcll(mask & ((1ULL << lane) - 1ULL));
                    if (pos < SMALL) cand2[pos] = cv;
                }
            }
        }
        __syncthreads();
        int nc2 = s_nc2;
        if (nc2 <= SMALL) { ncand = nc2; fromC2 = true; }
        else bigSort = true;                      // pathological (mass key ties)
    }

    // ---------------- Phase 3: descending sort --------------------------------
    unsigned long long vreg = 0ULL;
    if (!bigSort) {
        // register/shfl hybrid bitonic, P=1024 fixed, 1 element per thread
        const unsigned long long* src = fromC2 ? cand2 : cand;
        unsigned long long v = (tid < ncand) ? src[tid] : 0ULL;
        #pragma unroll
        for (int size = 2; size <= SMALL; size <<= 1) {
            #pragma unroll
            for (int stride = size >> 1; stride > 0; stride >>= 1) {
                unsigned long long o;
                if (stride < 64) {
                    o = shflXor64(v, stride);     // intra-wave: no barrier
                } else {
                    cand[tid] = v;
                    __syncthreads();
                    o = cand[tid ^ stride];
                    __syncthreads();
                }
                bool takeMax = (((tid & size) == 0) == ((tid & stride) == 0));
                unsigned long long mx = (v > o) ? v : o;
                unsigned long long mn = (v > o) ? o : v;
                v = takeMax ? mx : mn;
            }
        }
        cand[tid] = v;
        vreg = v;
        varr[tid] = (tid < ncand) ? (valOfKey((unsigned)(vreg >> 32)) / t) : NEG_BIG;
        __syncthreads();
    } else {
        // fallback: original LDS bitonic over up to CAP elements
        int P = 2; while (P < ncand) P <<= 1;
        for (int i = ncand + tid; i < P; i += NTHR) cand[i] = 0ULL;
        __syncthreads();
        for (int size = 2; size <= P; size <<= 1) {
            for (int stride = size >> 1; stride > 0; stride >>= 1) {
                for (int i = tid; i < P; i += NTHR) {
                    int j = i ^ stride;
                    if (j > i) {
                        unsigned long long a = cand[i], b = cand[j];
                        bool up = ((i & size) == 0);
                        bool sw = up ? (a < b) : (a > b);
                        if (sw) { cand[i] = b; cand[j] = a; }
                    }
                }
                __syncthreads();
            }
        }
        for (int i = tid; i < 1024; i += NTHR)
            varr[i] = (i < ncand) ? (valOfKey((unsigned)(cand[i] >> 32)) / t) : NEG_BIG;
        __syncthreads();
    }

    // ---------------- Phase 4: top-k/top-p/sample (numerics unchanged) --------
    const float m = varr[0];
    const float tkeyV = varr[k - 1];              // k-th largest v
    int ntop = k;                                 // expand ties at threshold
    while (ntop < ncand) {
        float vi = (ntop < 1024) ? varr[ntop]
                                 : (valOfKey((unsigned)(cand[ntop] >> 32)) / t);
        if (vi != tkeyV) break;
        ++ntop;
    }
    if (ntop > 1024) ntop = 1024;

    {
        float e = (tid < ntop) ? expf(varr[tid] - m) : 0.0f;
        Earr[tid] = e;
        sfx[tid] = e;
    }
    __syncthreads();
    for (int d = 1; d < 1024; d <<= 1) {          // inclusive suffix scan (verbatim)
        float t0 = (tid + d < 1024) ? sfx[tid + d] : 0.0f;
        __syncthreads();
        sfx[tid] += t0;
        __syncthreads();
    }
    const float Zp = sfx[0];
    const float cmp = 1.0f - p;
    if (tid == 0) { s_nkeep = 0; s_rank = 0; s_amax = 0ULL; }
    for (int i = tid; i < 64; i += NTHR) bitmap[i] = 0;
    __syncthreads();
    {
        int local = 0;
        for (int i = tid; i < ntop; i += NTHR)
            if (sfx[i] / Zp > cmp) local++;       // keep iff ascending-cum > 1-p
        #pragma unroll
        for (int d = 1; d < 64; d <<= 1) local += __shfl_xor(local, d);
        if (lane == 0 && local) atomicAdd(&s_nkeep, local);
    }
    __syncthreads();
    const int nkeep = s_nkeep;                    // >= 1
    if (tid == 0) {                               // boundary v-tie group
        float vb = varr[nkeep - 1];
        int g0 = nkeep - 1;
        while (g0 > 0 && varr[g0 - 1] == vb) --g0;
        int g1 = nkeep;
        while (g1 < ntop && varr[g1] == vb) ++g1;
        s_g0 = g0; s_g1 = g1;
    }
    __syncthreads();
    const int g0 = s_g0, g1 = s_g1;
    const int mkeep = nkeep - g0;
    // kept members of boundary group = mkeep HIGHEST vocab indices
    for (int i = g0 + tid; i < g1; i += NTHR) {
        unsigned gi = ~(unsigned)(cand[i] & 0xFFFFFFFFull);
        int rk = 0;
        for (int j = g0; j < g1; ++j) {
            unsigned gj = ~(unsigned)(cand[j] & 0xFFFFFFFFull);
            if (gj > gi) rk++;
        }
        flagArr[i] = (rk < mkeep) ? 1 : 0;
    }
    __syncthreads();

    const float Z2 = (nkeep < 1024) ? (Zp - sfx[nkeep]) : Zp;
    const float L = logf(Z2);

    // gumbel argmax over kept set (wave-reduced; max is order-independent)
    {
        unsigned long long lm = 0ULL;
        for (int i = tid; i < g1; i += NTHR) {
            if (i < g0 || flagArr[i]) {
                unsigned lo = (unsigned)(cand[i] & 0xFFFFFFFFull);
                unsigned gidx = ~lo;
                float u = urow[gidx];
                float q = -((u >= RMAX_F) ? RMAX_LOG_F : logf(u));
                float prob = Earr[i] / Z2;
                float ratio = greedy ? prob : (prob / q);
                unsigned long long comp = ((unsigned long long)__float_as_uint(ratio) << 32) | lo;
                if (comp > lm) lm = comp;
                if (gidx < 2048) atomicOr(&bitmap[gidx >> 5], 1u << (gidx & 31));
            }
        }
        #pragma unroll
        for (int d = 1; d < 64; d <<= 1) {
            unsigned long long o = shflXor64(lm, d);
            if (o > lm) lm = o;
        }
        if (lane == 0 && lm) atomicMax(&s_amax, lm);
    }
    __syncthreads();
    const unsigned samp_lo = (unsigned)(s_amax & 0xFFFFFFFFull);
    const unsigned samp = ~samp_lo;
    for (int i = tid; i < ntop; i += NTHR)
        if ((unsigned)(cand[i] & 0xFFFFFFFFull) == samp_lo) s_vs = varr[i];
    __syncthreads();
    const float lp_s = (s_vs - m) - L;
    {
        int local = 0;
        for (int i = tid; i < nkeep; i += NTHR)
            if ((varr[i] - m) - L > lp_s) local++;
        #pragma unroll
        for (int d = 1; d < 64; d <<= 1) local += __shfl_xor(local, d);
        if (lane == 0 && local) atomicAdd(&s_rank, local);
    }
    __syncthreads();

    // ---------------- Phase 5: outputs (parallel emission) --------------------
    // d_out (float): [B] sampled | [B,K+1] indices | [B,K+1] lp_vals | [B] ranks
    float* o_samp = out;
    float* o_idx  = out + B;
    float* o_lp   = out + B + (long long)B * (K + 1);
    float* o_rank = out + B + 2LL * B * (K + 1);
    const long long rowo = (long long)r * (K + 1);
    const int ntk = (nkeep < K) ? nkeep : K;

    // slot(i) = #kept before i's v-run + #kept in run with smaller vocab idx;
    // identical to the serial (v desc, idx asc) run walk (lax.top_k tie-break).
    if (tid < g1) {
        const int i = tid;
        bool kept = (i < g0) || flagArr[i];
        if (kept) {
            float v = varr[i];
            int rs, re, base;
            if (i >= g0) { rs = g0; re = g1; base = g0; }
            else {
                rs = i; while (rs > 0 && varr[rs - 1] == v) --rs;
                re = i + 1; while (re < g1 && varr[re] == v) ++re;
                base = rs;
            }
            if (base < ntk) {
                unsigned myidx = ~(unsigned)(cand[i] & 0xFFFFFFFFull);
                int cnt = 0;
                for (int j = rs; j < re; ++j) {
                    if (j == i) continue;
                    if (j >= g0 && !flagArr[j]) continue;
                    unsigned gj = ~(unsigned)(cand[j] & 0xFFFFFFFFull);
                    if (gj < myidx) cnt++;
                }
                int slot = base + cnt;
                if (slot < ntk) {
                    o_idx[rowo + 1 + slot] = (float)myidx;
                    o_lp[rowo + 1 + slot] = (v - m) - L;
                }
            }
        }
    }

    if (tid == 0) {
        o_samp[r] = (float)samp;
        o_idx[rowo] = (float)samp;
        o_lp[rowo] = lp_s;
        o_rank[r] = (float)s_rank;
        if (nkeep < K) {
            // fillers: smallest non-kept vocab indices, finite "-inf"
            int j = 0;
            for (int c = nkeep; c < K; ++c) {
                while (bitmap[j >> 5] & (1u << (j & 31))) ++j;
                o_idx[rowo + 1 + c] = (float)j;
                o_lp[rowo + 1 + c] = NEG_BIG;
                ++j;
            }
        }
    }
}

extern "C" void kernel_launch(void* const* d_in, const int* in_sizes, int n_in,
                              void* d_out, int out_size, void* d_ws, size_t ws_size,
                              hipStream_t stream) {
    const float* logits      = (const float*)d_in[0];
    const float* temperature = (const float*)d_in[1];
    const int*   top_k       = (const int*)d_in[2];
    const float* top_p       = (const float*)d_in[3];
    const float* gumbel      = (const float*)d_in[4];
    int B = in_sizes[1];
    int V = in_sizes[0] / B;
    int K = (out_size / B - 4) / 2;
    sampler_kernel<<<B, NTHR, 0, stream>>>(logits, temperature, top_k, top_p,
                                           gumbel, (float*)d_out, B, V, K);
}

// Round 2
// 268.044 us; speedup vs baseline: 1.1830x; 1.0489x over previous
//
#include <hip/hip_runtime.h>
#include <math.h>

#define NTHR 1024
#define CAP 8192
#define BINS 4096
#define SMALL 1024
#define GUARD 16u
#define SS 4096

#define RMAX_F 0.9999999403953552f
#define RMAX_LOG_F -5.960464477539063e-08f
#define NEG_BIG -3.0e38f

__device__ __forceinline__ unsigned keyOf(float v) {
    unsigned b = __float_as_uint(v);
    return (b & 0x80000000u) ? ~b : (b | 0x80000000u);
}
__device__ __forceinline__ float valOfKey(unsigned k) {
    unsigned b = (k & 0x80000000u) ? (k ^ 0x80000000u) : ~k;
    return __uint_as_float(b);
}
__device__ __forceinline__ unsigned long long shflXor64(unsigned long long v, int m) {
    int lo = __shfl_xor((int)(unsigned)v, m);
    int hi = __shfl_xor((int)(unsigned)(v >> 32), m);
    return ((unsigned long long)(unsigned)hi << 32) | (unsigned)lo;
}

// One block per row, 1024 threads. R2: single-pass front end.
//  P0: 4096-sample subsample histogram (12-bit bins) -> speculative threshold T
//      targeting ~clamp(3k+500,700,3500) survivors (CAP raised to 8192 so the
//      overshoot tail is negligible). 2 barriers.
//  P1: ONE full pass: predicated per-thread compaction of (key, ~idx) for
//      l >= T. No global histogram, no per-element ballot.
//      Exact post-check: k <= ncand <= CAP, else verbatim old two-pass fallback
//      (full 12-bit histogram + exact selection + compaction) -> always correct.
//  P2.5: exact kth key among candidates via in-LDS refine; fast path starts
//      from empty prefix (4 x 8-bit rounds); fallback keeps its known prefix.
//      16-ulp guard recompact to <=1024 (v-tie span bound) -- unchanged.
//  P3/P4/P5: bit-identical to R1 (register/shfl bitonic, sfx tree scan
//      verbatim, wave-reduced atomics, parallel emission).
__global__ __launch_bounds__(NTHR) void sampler_kernel(
    const float* __restrict__ logits,
    const float* __restrict__ temperature,
    const int* __restrict__ top_kv,
    const float* __restrict__ top_pv,
    const float* __restrict__ gumbel,
    float* __restrict__ out,
    int B, int V, int K)
{
    const int r = blockIdx.x;
    const int tid = threadIdx.x;
    const int lane = tid & 63;
    const int wid = tid >> 6;

    __shared__ unsigned long long cand[CAP];      // 64 KB; aliased as hist
    __shared__ unsigned long long cand2[SMALL];   // 8 KB refine target
    __shared__ unsigned refHist[512];             // 2 KB refine histogram
    __shared__ int wtotI[16];
    __shared__ float varr[1024];
    __shared__ float Earr[1024];
    __shared__ float sfx[1024];
    __shared__ unsigned char flagArr[1024];
    __shared__ unsigned bitmap[64];
    __shared__ unsigned s_prefix;
    __shared__ int s_cntgt, s_total, s_lvl;
    __shared__ int s_ncand, s_nc2, s_nkeep, s_rank, s_g0, s_g1;
    __shared__ unsigned long long s_amax;
    __shared__ float s_vs;

    unsigned* hist = (unsigned*)cand;             // [BINS*2] (2 privatized copies)

    const float* row = logits + (long long)r * V;
    const float* urow = gumbel + (long long)r * V;

    float traw = temperature[r];
    bool greedy = traw < 1e-5f;
    float t = greedy ? 1.0f : traw;               // ref: temp<eps -> divide by 1.0
    int k = top_kv[r];
    if (k < 1) k = 1;
    if (k > V) k = V;
    float p = top_pv[r];

    const float4* row4 = (const float4*)row;
    const int V4 = V >> 2;
    const int Vt = V4 << 2;
    const unsigned cpy = tid & 1u;

#define H4(v4) do { \
        atomicAdd(&hist[((keyOf((v4).x) >> 20) << 1) | cpy], 1u); \
        atomicAdd(&hist[((keyOf((v4).y) >> 20) << 1) | cpy], 1u); \
        atomicAdd(&hist[((keyOf((v4).z) >> 20) << 1) | cpy], 1u); \
        atomicAdd(&hist[((keyOf((v4).w) >> 20) << 1) | cpy], 1u); \
    } while (0)
#define SPEC1(val, gidx_, thr_) do { \
        float _v = (val); \
        if (_v >= (thr_)) { \
            int _pos = atomicAdd(&s_ncand, 1); \
            if (_pos < CAP) \
                cand[_pos] = ((unsigned long long)keyOf(_v) << 32) | (unsigned)(~(unsigned)(gidx_)); \
        } \
    } while (0)

    // ---------------- Phase 0: subsample -> speculative threshold ------------
    for (int i = tid; i < BINS * 2; i += NTHR) hist[i] = 0;
    __syncthreads();
    {
        int f4pos = (int)(((long long)tid * V4) >> 10);   // NTHR = 1024
        float4 sv = row4[f4pos];                          // 4096 spread samples
        H4(sv);
    }
    __syncthreads();
    int ts;                                               // sample-count target
    {
        int tc = 3 * k + 500;
        if (tc > 3500) tc = 3500;
        if (tc < 700) tc = 700;
        ts = (int)(((long long)tc * SS + V - 1) / V);
        if (ts < 4) ts = 4;
    }
    {
        int base = tid << 2;
        int cs = 0;
        #pragma unroll
        for (int j = 0; j < 4; ++j)
            cs += (int)(hist[(base + j) * 2] + hist[(base + j) * 2 + 1]);
        int vv = cs;
        #pragma unroll
        for (int d = 1; d < 64; d <<= 1) {
            int o = __shfl_down(vv, d);
            if (lane + d < 64) vv += o;
        }
        if (lane == 0) wtotI[wid] = vv;
        __syncthreads();
        int off = 0;
        for (int w = wid + 1; w < 16; ++w) off += wtotI[w];
        int mine = vv + off;
        int above = mine - cs;
        if (mine >= ts && above < ts) {                   // exactly one thread
            int run = above;
            for (int b = base + 3; b >= base; --b) {
                int mb = (int)(hist[b * 2] + hist[b * 2 + 1]);
                if (run + mb >= ts) { s_prefix = (unsigned)b; break; }
                run += mb;
            }
        }
        if (tid == 0) s_ncand = 0;
        __syncthreads();
    }
    unsigned tlo = s_prefix << 20;
    float thrF = valOfKey(tlo);

    // ---------------- Phase 1: single-pass speculative compaction ------------
    {
        int i = tid;
        for (; i + 3 * NTHR < V4; i += 4 * NTHR) {
            float4 a = row4[i];
            float4 b = row4[i + NTHR];
            float4 c = row4[i + 2 * NTHR];
            float4 d = row4[i + 3 * NTHR];
            SPEC1(a.x, i * 4 + 0, thrF); SPEC1(a.y, i * 4 + 1, thrF);
            SPEC1(a.z, i * 4 + 2, thrF); SPEC1(a.w, i * 4 + 3, thrF);
            SPEC1(b.x, (i + NTHR) * 4 + 0, thrF); SPEC1(b.y, (i + NTHR) * 4 + 1, thrF);
            SPEC1(b.z, (i + NTHR) * 4 + 2, thrF); SPEC1(b.w, (i + NTHR) * 4 + 3, thrF);
            SPEC1(c.x, (i + 2 * NTHR) * 4 + 0, thrF); SPEC1(c.y, (i + 2 * NTHR) * 4 + 1, thrF);
            SPEC1(c.z, (i + 2 * NTHR) * 4 + 2, thrF); SPEC1(c.w, (i + 2 * NTHR) * 4 + 3, thrF);
            SPEC1(d.x, (i + 3 * NTHR) * 4 + 0, thrF); SPEC1(d.y, (i + 3 * NTHR) * 4 + 1, thrF);
            SPEC1(d.z, (i + 3 * NTHR) * 4 + 2, thrF); SPEC1(d.w, (i + 3 * NTHR) * 4 + 3, thrF);
        }
        for (; i < V4; i += NTHR) {
            float4 a = row4[i];
            SPEC1(a.x, i * 4 + 0, thrF); SPEC1(a.y, i * 4 + 1, thrF);
            SPEC1(a.z, i * 4 + 2, thrF); SPEC1(a.w, i * 4 + 3, thrF);
        }
        for (int ii = Vt + tid; ii < V; ii += NTHR)
            SPEC1(row[ii], ii, thrF);
    }
    __syncthreads();
    int ncand = s_ncand;                                  // unclamped count
    const bool fastok = (ncand >= k && ncand <= CAP);

    // ---------------- Fallback: verbatim two-pass exact front end ------------
    if (!fastok) {
        for (int i = tid; i < BINS * 2; i += NTHR) hist[i] = 0;
        __syncthreads();
        {
            int i = tid;
            for (; i + 3 * NTHR < V4; i += 4 * NTHR) {
                float4 a = row4[i];
                float4 b = row4[i + NTHR];
                float4 c = row4[i + 2 * NTHR];
                float4 d = row4[i + 3 * NTHR];
                H4(a); H4(b); H4(c); H4(d);
            }
            for (; i < V4; i += NTHR) { float4 a = row4[i]; H4(a); }
            for (int ii = Vt + tid; ii < V; ii += NTHR)
                atomicAdd(&hist[((keyOf(row[ii]) >> 20) << 1) | cpy], 1u);
        }
        __syncthreads();
        {
            int base = tid << 2;
            int cs = 0;
            #pragma unroll
            for (int j = 0; j < 4; ++j)
                cs += (int)(hist[(base + j) * 2] + hist[(base + j) * 2 + 1]);
            int vv = cs;
            #pragma unroll
            for (int d = 1; d < 64; d <<= 1) {
                int o = __shfl_down(vv, d);
                if (lane + d < 64) vv += o;
            }
            if (lane == 0) wtotI[wid] = vv;
            __syncthreads();
            int off = 0;
            for (int w = wid + 1; w < 16; ++w) off += wtotI[w];
            int mine = vv + off;
            int above = mine - cs;
            if (mine >= k && above < k) {
                int run = above;
                for (int b = base + 3; b >= base; --b) {
                    int mb = (int)(hist[b * 2] + hist[b * 2 + 1]);
                    if (run + mb >= k) {
                        s_prefix = (unsigned)b; s_cntgt = run; s_total = run + mb; s_lvl = 0;
                        break;
                    }
                    run += mb;
                }
            }
        }
        for (int level = 1; level <= 2; ++level) {
            __syncthreads();
            if (s_total <= CAP) break;
            for (int i = tid; i < 512; i += NTHR) hist[i] = 0;
            __syncthreads();
            unsigned pfx = s_prefix;
            const int msh = 32 - (12 + 8 * (level - 1));
            const int bsh = msh - 8;
            for (int i = tid; i < V4; i += NTHR) {
                float4 l4 = row4[i];
                float vv4[4] = { l4.x, l4.y, l4.z, l4.w };
                #pragma unroll
                for (int j = 0; j < 4; ++j) {
                    unsigned key = keyOf(vv4[j]);
                    if ((key >> msh) == pfx)
                        atomicAdd(&hist[(((key >> bsh) & 255u) << 1) | cpy], 1u);
                }
            }
            for (int i = Vt + tid; i < V; i += NTHR) {
                unsigned key = keyOf(row[i]);
                if ((key >> msh) == pfx)
                    atomicAdd(&hist[(((key >> bsh) & 255u) << 1) | cpy], 1u);
            }
            __syncthreads();
            if (tid == 0) {
                int run = s_cntgt;
                for (int b = 255; b >= 0; --b) {
                    int mb = (int)(hist[b * 2] + hist[b * 2 + 1]);
                    if (run + mb >= k) {
                        s_prefix = (pfx << 8) | (unsigned)b; s_cntgt = run; s_total = run + mb;
                        break;
                    }
                    run += mb;
                }
                s_lvl = level;
            }
        }
        __syncthreads();
        tlo = s_prefix << (20 - 8 * s_lvl);
        thrF = valOfKey(tlo);
        if (tid == 0) s_ncand = 0;
        __syncthreads();
        {
            int i = tid;
            for (; i + 3 * NTHR < V4; i += 4 * NTHR) {
                float4 a = row4[i];
                float4 b = row4[i + NTHR];
                float4 c = row4[i + 2 * NTHR];
                float4 d = row4[i + 3 * NTHR];
                SPEC1(a.x, i * 4 + 0, thrF); SPEC1(a.y, i * 4 + 1, thrF);
                SPEC1(a.z, i * 4 + 2, thrF); SPEC1(a.w, i * 4 + 3, thrF);
                SPEC1(b.x, (i + NTHR) * 4 + 0, thrF); SPEC1(b.y, (i + NTHR) * 4 + 1, thrF);
                SPEC1(b.z, (i + NTHR) * 4 + 2, thrF); SPEC1(b.w, (i + NTHR) * 4 + 3, thrF);
                SPEC1(c.x, (i + 2 * NTHR) * 4 + 0, thrF); SPEC1(c.y, (i + 2 * NTHR) * 4 + 1, thrF);
                SPEC1(c.z, (i + 2 * NTHR) * 4 + 2, thrF); SPEC1(c.w, (i + 2 * NTHR) * 4 + 3, thrF);
                SPEC1(d.x, (i + 3 * NTHR) * 4 + 0, thrF); SPEC1(d.y, (i + 3 * NTHR) * 4 + 1, thrF);
                SPEC1(d.z, (i + 3 * NTHR) * 4 + 2, thrF); SPEC1(d.w, (i + 3 * NTHR) * 4 + 3, thrF);
            }
            for (; i < V4; i += NTHR) {
                float4 a = row4[i];
                SPEC1(a.x, i * 4 + 0, thrF); SPEC1(a.y, i * 4 + 1, thrF);
                SPEC1(a.z, i * 4 + 2, thrF); SPEC1(a.w, i * 4 + 3, thrF);
            }
            for (int ii = Vt + tid; ii < V; ii += NTHR)
                SPEC1(row[ii], ii, thrF);
        }
        __syncthreads();
        ncand = s_ncand;
        if (ncand > CAP) ncand = CAP;
        if (k > ncand) k = ncand;
    }
    if (k > ncand) k = ncand;                             // safety (fast: no-op)

    // ------- Phase 2.5: in-LDS exact-kth refine + recompact (ncand > 1024) ----
    bool fromC2 = false;
    bool bigSort = false;
    if (ncand > SMALL) {
        unsigned pfx; int run; int bb;
        if (fastok) { pfx = 0u; run = 0; bb = 32; }       // full key unknown
        else { pfx = s_prefix; run = s_cntgt; bb = 20 - 8 * s_lvl; }
        while (bb > 0) {
            int step = (bb >= 8) ? 8 : bb;
            bb -= step;
            int nbins = 1 << step;
            for (int i = tid; i < nbins * 2; i += NTHR) refHist[i] = 0;
            __syncthreads();
            {
                int sh = bb + step;
                for (int i = tid; i < ncand; i += NTHR) {
                    unsigned key = (unsigned)(cand[i] >> 32);
                    bool in = (sh >= 32) || ((key >> sh) == pfx);
                    if (in)
                        atomicAdd(&refHist[(((key >> bb) & (unsigned)(nbins - 1)) << 1) | cpy], 1u);
                }
            }
            __syncthreads();
            int cnt = 0;
            if (tid < 256) cnt = (tid < nbins) ? (int)(refHist[tid * 2] + refHist[tid * 2 + 1]) : 0;
            int vv = cnt;
            #pragma unroll
            for (int d = 1; d < 64; d <<= 1) {
                int o = __shfl_down(vv, d);
                if (lane + d < 64) vv += o;
            }
            if (tid < 256 && lane == 0) wtotI[wid] = vv;
            __syncthreads();
            if (tid < 256) {
                int off = 0;
                for (int w = wid + 1; w < 4; ++w) off += wtotI[w];
                int incl = vv + off;
                int abv = incl - cnt;
                int kk = k - run;
                if (incl >= kk && abv < kk) {             // exactly one bin
                    s_prefix = (pfx << step) | (unsigned)tid;
                    s_cntgt = run + abv;
                }
            }
            __syncthreads();
            pfx = s_prefix;
            run = s_cntgt;
        }
        // pfx == exact kth-largest key; keep >= kth-16ulp (v-tie guard, span<=2)
        unsigned tref = (pfx >= tlo + GUARD) ? (pfx - GUARD) : tlo;
        if (tid == 0) s_nc2 = 0;
        __syncthreads();
        for (int i = tid; i < ncand; i += NTHR) {
            unsigned long long cv = cand[i];
            bool pred = ((unsigned)(cv >> 32) >= tref);
            unsigned long long mask = __ballot(pred ? 1 : 0);
            if (mask) {
                int leader = __ffsll(mask) - 1;
                int cnt2 = __popcll(mask);
                int bpos = 0;
                if (lane == leader) bpos = atomicAdd(&s_nc2, cnt2);
                bpos = __shfl(bpos, leader);
                if (pred) {
                    int pos = bpos + __popcll(mask & ((1ULL << lane) - 1ULL));
                    if (pos < SMALL) cand2[pos] = cv;
                }
            }
        }
        __syncthreads();
        int nc2 = s_nc2;
        if (nc2 <= SMALL) { ncand = nc2; fromC2 = true; }
        else bigSort = true;                              // pathological key ties
    }

    // ---------------- Phase 3: descending sort --------------------------------
    if (!bigSort) {
        // register/shfl hybrid bitonic, P=1024 fixed, 1 element per thread
        const unsigned long long* src = fromC2 ? cand2 : cand;
        unsigned long long v = (tid < ncand) ? src[tid] : 0ULL;
        #pragma unroll
        for (int size = 2; size <= SMALL; size <<= 1) {
            #pragma unroll
            for (int stride = size >> 1; stride > 0; stride >>= 1) {
                unsigned long long o;
                if (stride < 64) {
                    o = shflXor64(v, stride);             // intra-wave: no barrier
                } else {
                    cand[tid] = v;
                    __syncthreads();
                    o = cand[tid ^ stride];
                    __syncthreads();
                }
                bool takeMax = (((tid & size) == 0) == ((tid & stride) == 0));
                unsigned long long mx = (v > o) ? v : o;
                unsigned long long mn = (v > o) ? o : v;
                v = takeMax ? mx : mn;
            }
        }
        cand[tid] = v;
        varr[tid] = (tid < ncand) ? (valOfKey((unsigned)(v >> 32)) / t) : NEG_BIG;
        __syncthreads();
    } else {
        // fallback: LDS bitonic over up to CAP elements
        int P = 2; while (P < ncand) P <<= 1;
        for (int i = ncand + tid; i < P; i += NTHR) cand[i] = 0ULL;
        __syncthreads();
        for (int size = 2; size <= P; size <<= 1) {
            for (int stride = size >> 1; stride > 0; stride >>= 1) {
                for (int i = tid; i < P; i += NTHR) {
                    int j = i ^ stride;
                    if (j > i) {
                        unsigned long long a = cand[i], b = cand[j];
                        bool up = ((i & size) == 0);
                        bool sw = up ? (a < b) : (a > b);
                        if (sw) { cand[i] = b; cand[j] = a; }
                    }
                }
                __syncthreads();
            }
        }
        for (int i = tid; i < 1024; i += NTHR)
            varr[i] = (i < ncand) ? (valOfKey((unsigned)(cand[i] >> 32)) / t) : NEG_BIG;
        __syncthreads();
    }

    // ---------------- Phase 4: top-k/top-p/sample (numerics unchanged) --------
    const float m = varr[0];
    const float tkeyV = varr[k - 1];              // k-th largest v
    int ntop = k;                                 // expand ties at threshold
    while (ntop < ncand) {
        float vi = (ntop < 1024) ? varr[ntop]
                                 : (valOfKey((unsigned)(cand[ntop] >> 32)) / t);
        if (vi != tkeyV) break;
        ++ntop;
    }
    if (ntop > 1024) ntop = 1024;

    {
        float e = (tid < ntop) ? expf(varr[tid] - m) : 0.0f;
        Earr[tid] = e;
        sfx[tid] = e;
    }
    __syncthreads();
    for (int d = 1; d < 1024; d <<= 1) {          // inclusive suffix scan (verbatim)
        float t0 = (tid + d < 1024) ? sfx[tid + d] : 0.0f;
        __syncthreads();
        sfx[tid] += t0;
        __syncthreads();
    }
    const float Zp = sfx[0];
    const float cmp = 1.0f - p;
    if (tid == 0) { s_nkeep = 0; s_rank = 0; s_amax = 0ULL; }
    for (int i = tid; i < 64; i += NTHR) bitmap[i] = 0;
    __syncthreads();
    {
        int local = 0;
        for (int i = tid; i < ntop; i += NTHR)
            if (sfx[i] / Zp > cmp) local++;       // keep iff ascending-cum > 1-p
        #pragma unroll
        for (int d = 1; d < 64; d <<= 1) local += __shfl_xor(local, d);
        if (lane == 0 && local) atomicAdd(&s_nkeep, local);
    }
    __syncthreads();
    const int nkeep = s_nkeep;                    // >= 1
    if (tid == 0) {                               // boundary v-tie group
        float vb = varr[nkeep - 1];
        int g0 = nkeep - 1;
        while (g0 > 0 && varr[g0 - 1] == vb) --g0;
        int g1 = nkeep;
        while (g1 < ntop && varr[g1] == vb) ++g1;
        s_g0 = g0; s_g1 = g1;
    }
    __syncthreads();
    const int g0 = s_g0, g1 = s_g1;
    const int mkeep = nkeep - g0;
    // kept members of boundary group = mkeep HIGHEST vocab indices
    for (int i = g0 + tid; i < g1; i += NTHR) {
        unsigned gi = ~(unsigned)(cand[i] & 0xFFFFFFFFull);
        int rk = 0;
        for (int j = g0; j < g1; ++j) {
            unsigned gj = ~(unsigned)(cand[j] & 0xFFFFFFFFull);
            if (gj > gi) rk++;
        }
        flagArr[i] = (rk < mkeep) ? 1 : 0;
    }
    __syncthreads();

    const float Z2 = (nkeep < 1024) ? (Zp - sfx[nkeep]) : Zp;
    const float L = logf(Z2);

    // gumbel argmax over kept set (wave-reduced; max is order-independent)
    {
        unsigned long long lm = 0ULL;
        for (int i = tid; i < g1; i += NTHR) {
            if (i < g0 || flagArr[i]) {
                unsigned lo = (unsigned)(cand[i] & 0xFFFFFFFFull);
                unsigned gidx = ~lo;
                float u = urow[gidx];
                float q = -((u >= RMAX_F) ? RMAX_LOG_F : logf(u));
                float prob = Earr[i] / Z2;
                float ratio = greedy ? prob : (prob / q);
                unsigned long long comp = ((unsigned long long)__float_as_uint(ratio) << 32) | lo;
                if (comp > lm) lm = comp;
                if (gidx < 2048) atomicOr(&bitmap[gidx >> 5], 1u << (gidx & 31));
            }
        }
        #pragma unroll
        for (int d = 1; d < 64; d <<= 1) {
            unsigned long long o = shflXor64(lm, d);
            if (o > lm) lm = o;
        }
        if (lane == 0 && lm) atomicMax(&s_amax, lm);
    }
    __syncthreads();
    const unsigned samp_lo = (unsigned)(s_amax & 0xFFFFFFFFull);
    const unsigned samp = ~samp_lo;
    for (int i = tid; i < ntop; i += NTHR)
        if ((unsigned)(cand[i] & 0xFFFFFFFFull) == samp_lo) s_vs = varr[i];
    __syncthreads();
    const float lp_s = (s_vs - m) - L;
    {
        int local = 0;
        for (int i = tid; i < nkeep; i += NTHR)
            if ((varr[i] - m) - L > lp_s) local++;
        #pragma unroll
        for (int d = 1; d < 64; d <<= 1) local += __shfl_xor(local, d);
        if (lane == 0 && local) atomicAdd(&s_rank, local);
    }
    __syncthreads();

    // ---------------- Phase 5: outputs (parallel emission) --------------------
    // d_out (float): [B] sampled | [B,K+1] indices | [B,K+1] lp_vals | [B] ranks
    float* o_samp = out;
    float* o_idx  = out + B;
    float* o_lp   = out + B + (long long)B * (K + 1);
    float* o_rank = out + B + 2LL * B * (K + 1);
    const long long rowo = (long long)r * (K + 1);
    const int ntk = (nkeep < K) ? nkeep : K;

    // slot(i) = #kept before i's v-run + #kept in run with smaller vocab idx;
    // identical to the serial (v desc, idx asc) run walk (lax.top_k tie-break).
    if (tid < g1) {
        const int i = tid;
        bool kept = (i < g0) || flagArr[i];
        if (kept) {
            float v = varr[i];
            int rs, re, base;
            if (i >= g0) { rs = g0; re = g1; base = g0; }
            else {
                rs = i; while (rs > 0 && varr[rs - 1] == v) --rs;
                re = i + 1; while (re < g1 && varr[re] == v) ++re;
                base = rs;
            }
            if (base < ntk) {
                unsigned myidx = ~(unsigned)(cand[i] & 0xFFFFFFFFull);
                int cnt = 0;
                for (int j = rs; j < re; ++j) {
                    if (j == i) continue;
                    if (j >= g0 && !flagArr[j]) continue;
                    unsigned gj = ~(unsigned)(cand[j] & 0xFFFFFFFFull);
                    if (gj < myidx) cnt++;
                }
                int slot = base + cnt;
                if (slot < ntk) {
                    o_idx[rowo + 1 + slot] = (float)myidx;
                    o_lp[rowo + 1 + slot] = (v - m) - L;
                }
            }
        }
    }

    if (tid == 0) {
        o_samp[r] = (float)samp;
        o_idx[rowo] = (float)samp;
        o_lp[rowo] = lp_s;
        o_rank[r] = (float)s_rank;
        if (nkeep < K) {
            // fillers: smallest non-kept vocab indices, finite "-inf"
            int j = 0;
            for (int c = nkeep; c < K; ++c) {
                while (bitmap[j >> 5] & (1u << (j & 31))) ++j;
                o_idx[rowo + 1 + c] = (float)j;
                o_lp[rowo + 1 + c] = NEG_BIG;
                ++j;
            }
        }
    }
}

extern "C" void kernel_launch(void* const* d_in, const int* in_sizes, int n_in,
                              void* d_out, int out_size, void* d_ws, size_t ws_size,
                              hipStream_t stream) {
    const float* logits      = (const float*)d_in[0];
    const float* temperature = (const float*)d_in[1];
    const int*   top_k       = (const int*)d_in[2];
    const float* top_p       = (const float*)d_in[3];
    const float* gumbel      = (const float*)d_in[4];
    int B = in_sizes[1];
    int V = in_sizes[0] / B;
    int K = (out_size / B - 4) / 2;
    sampler_kernel<<<B, NTHR, 0, stream>>>(logits, temperature, top_k, top_p,
                                           gumbel, (float*)d_out, B, V, K);
}

// Round 3
// 265.431 us; speedup vs baseline: 1.1946x; 1.0098x over previous
//
#include <hip/hip_runtime.h>
#include <math.h>

#define NTHR 1024
#define CAP 8192
#define BINS 4096
#define SMALL 1024
#define GUARD 16u
#define SS 4096

#define RMAX_F 0.9999999403953552f
#define RMAX_LOG_F -5.960464477539063e-08f
#define NEG_BIG -3.0e38f

__device__ __forceinline__ unsigned keyOf(float v) {
    unsigned b = __float_as_uint(v);
    return (b & 0x80000000u) ? ~b : (b | 0x80000000u);
}
__device__ __forceinline__ float valOfKey(unsigned k) {
    unsigned b = (k & 0x80000000u) ? (k ^ 0x80000000u) : ~k;
    return __uint_as_float(b);
}
__device__ __forceinline__ unsigned long long shflXor64(unsigned long long v, int m) {
    int lo = __shfl_xor((int)(unsigned)v, m);
    int hi = __shfl_xor((int)(unsigned)(v >> 32), m);
    return ((unsigned long long)(unsigned)hi << 32) | (unsigned)lo;
}

// One block per row, 1024 threads. R3: barrier / LDS-serialization reduction.
//  P0: subsample -> speculative threshold (target ~2k+400 survivors, was 3k+500).
//  P1: single predicated compaction pass (unchanged structure).
//  Fallback: verbatim exact two-pass front end when ncand outside [k, CAP].
//  P2.5: adaptive refine: early-stop when bound(kept) <= 1008; cut at bin floor
//      minus GUARD keeps a SUPERSET of the exact-kth 16-ulp band -> downstream
//      exact-k/tie logic unaffected. Histogram is 16-way lane-privatized with
//      257 stride (no hot-bin same-address serialization, no bank conflicts).
//  P3: hybrid bitonic; LDS exchanges now 1 barrier each via 2-segment
//      ping-pong (10 passes, even -> final cand[0..1023] write is race-free).
//  P4: sfx scan 1 barrier/step via double buffer; identical addition order ->
//      bit-identical. Init of s_nkeep/s_rank/s_amax/bitmap fused pre-scan.
//  P5: parallel emission (unchanged).
__global__ __launch_bounds__(NTHR) void sampler_kernel(
    const float* __restrict__ logits,
    const float* __restrict__ temperature,
    const int* __restrict__ top_kv,
    const float* __restrict__ top_pv,
    const float* __restrict__ gumbel,
    float* __restrict__ out,
    int B, int V, int K)
{
    const int r = blockIdx.x;
    const int tid = threadIdx.x;
    const int lane = tid & 63;
    const int wid = tid >> 6;

    __shared__ unsigned long long cand[CAP];      // 64 KB; aliased as hist
    __shared__ unsigned long long cand2[SMALL];   // 8 KB refine target
    __shared__ unsigned refHist[16 * 257];        // 16.4 KB privatized refine hist
    __shared__ int wtotI[16];
    __shared__ float varr[1024];
    __shared__ float Earr[1024];
    __shared__ float sfx[1024];
    __shared__ float sfx2[1024];
    __shared__ unsigned char flagArr[1024];
    __shared__ unsigned bitmap[64];
    __shared__ unsigned s_prefix;
    __shared__ int s_cntgt, s_total, s_lvl;
    __shared__ int s_ncand, s_nc2, s_nkeep, s_rank, s_g0, s_g1;
    __shared__ unsigned long long s_amax;
    __shared__ float s_vs;

    unsigned* hist = (unsigned*)cand;             // [BINS*2] (2 privatized copies)

    const float* row = logits + (long long)r * V;
    const float* urow = gumbel + (long long)r * V;

    float traw = temperature[r];
    bool greedy = traw < 1e-5f;
    float t = greedy ? 1.0f : traw;               // ref: temp<eps -> divide by 1.0
    int k = top_kv[r];
    if (k < 1) k = 1;
    if (k > V) k = V;
    float p = top_pv[r];

    const float4* row4 = (const float4*)row;
    const int V4 = V >> 2;
    const int Vt = V4 << 2;
    const unsigned cpy = tid & 1u;

#define H4(v4) do { \
        atomicAdd(&hist[((keyOf((v4).x) >> 20) << 1) | cpy], 1u); \
        atomicAdd(&hist[((keyOf((v4).y) >> 20) << 1) | cpy], 1u); \
        atomicAdd(&hist[((keyOf((v4).z) >> 20) << 1) | cpy], 1u); \
        atomicAdd(&hist[((keyOf((v4).w) >> 20) << 1) | cpy], 1u); \
    } while (0)
#define SPEC1(val, gidx_, thr_) do { \
        float _v = (val); \
        if (_v >= (thr_)) { \
            int _pos = atomicAdd(&s_ncand, 1); \
            if (_pos < CAP) \
                cand[_pos] = ((unsigned long long)keyOf(_v) << 32) | (unsigned)(~(unsigned)(gidx_)); \
        } \
    } while (0)

    // ---------------- Phase 0: subsample -> speculative threshold ------------
    for (int i = tid; i < BINS * 2; i += NTHR) hist[i] = 0;
    __syncthreads();
    {
        int f4pos = (int)(((long long)tid * V4) >> 10);   // NTHR = 1024
        float4 sv = row4[f4pos];                          // 4096 spread samples
        H4(sv);
    }
    __syncthreads();
    int ts;                                               // sample-count target
    {
        int tc = 2 * k + 400;
        if (tc > 2400) tc = 2400;
        if (tc < 600) tc = 600;
        ts = (int)(((long long)tc * SS + V - 1) / V);
        if (ts < 4) ts = 4;
    }
    {
        int base = tid << 2;
        int cs = 0;
        #pragma unroll
        for (int j = 0; j < 4; ++j)
            cs += (int)(hist[(base + j) * 2] + hist[(base + j) * 2 + 1]);
        int vv = cs;
        #pragma unroll
        for (int d = 1; d < 64; d <<= 1) {
            int o = __shfl_down(vv, d);
            if (lane + d < 64) vv += o;
        }
        if (lane == 0) wtotI[wid] = vv;
        __syncthreads();
        int off = 0;
        for (int w = wid + 1; w < 16; ++w) off += wtotI[w];
        int mine = vv + off;
        int above = mine - cs;
        if (mine >= ts && above < ts) {                   // exactly one thread
            int run = above;
            for (int b = base + 3; b >= base; --b) {
                int mb = (int)(hist[b * 2] + hist[b * 2 + 1]);
                if (run + mb >= ts) { s_prefix = (unsigned)b; break; }
                run += mb;
            }
        }
        if (tid == 0) s_ncand = 0;
        __syncthreads();
    }
    unsigned tlo = s_prefix << 20;
    float thrF = valOfKey(tlo);

    // ---------------- Phase 1: single-pass speculative compaction ------------
    {
        int i = tid;
        for (; i + 3 * NTHR < V4; i += 4 * NTHR) {
            float4 a = row4[i];
            float4 b = row4[i + NTHR];
            float4 c = row4[i + 2 * NTHR];
            float4 d = row4[i + 3 * NTHR];
            SPEC1(a.x, i * 4 + 0, thrF); SPEC1(a.y, i * 4 + 1, thrF);
            SPEC1(a.z, i * 4 + 2, thrF); SPEC1(a.w, i * 4 + 3, thrF);
            SPEC1(b.x, (i + NTHR) * 4 + 0, thrF); SPEC1(b.y, (i + NTHR) * 4 + 1, thrF);
            SPEC1(b.z, (i + NTHR) * 4 + 2, thrF); SPEC1(b.w, (i + NTHR) * 4 + 3, thrF);
            SPEC1(c.x, (i + 2 * NTHR) * 4 + 0, thrF); SPEC1(c.y, (i + 2 * NTHR) * 4 + 1, thrF);
            SPEC1(c.z, (i + 2 * NTHR) * 4 + 2, thrF); SPEC1(c.w, (i + 2 * NTHR) * 4 + 3, thrF);
            SPEC1(d.x, (i + 3 * NTHR) * 4 + 0, thrF); SPEC1(d.y, (i + 3 * NTHR) * 4 + 1, thrF);
            SPEC1(d.z, (i + 3 * NTHR) * 4 + 2, thrF); SPEC1(d.w, (i + 3 * NTHR) * 4 + 3, thrF);
        }
        for (; i < V4; i += NTHR) {
            float4 a = row4[i];
            SPEC1(a.x, i * 4 + 0, thrF); SPEC1(a.y, i * 4 + 1, thrF);
            SPEC1(a.z, i * 4 + 2, thrF); SPEC1(a.w, i * 4 + 3, thrF);
        }
        for (int ii = Vt + tid; ii < V; ii += NTHR)
            SPEC1(row[ii], ii, thrF);
    }
    __syncthreads();
    int ncand = s_ncand;                                  // unclamped count
    const bool fastok = (ncand >= k && ncand <= CAP);

    // ---------------- Fallback: verbatim two-pass exact front end ------------
    if (!fastok) {
        for (int i = tid; i < BINS * 2; i += NTHR) hist[i] = 0;
        __syncthreads();
        {
            int i = tid;
            for (; i + 3 * NTHR < V4; i += 4 * NTHR) {
                float4 a = row4[i];
                float4 b = row4[i + NTHR];
                float4 c = row4[i + 2 * NTHR];
                float4 d = row4[i + 3 * NTHR];
                H4(a); H4(b); H4(c); H4(d);
            }
            for (; i < V4; i += NTHR) { float4 a = row4[i]; H4(a); }
            for (int ii = Vt + tid; ii < V; ii += NTHR)
                atomicAdd(&hist[((keyOf(row[ii]) >> 20) << 1) | cpy], 1u);
        }
        __syncthreads();
        {
            int base = tid << 2;
            int cs = 0;
            #pragma unroll
            for (int j = 0; j < 4; ++j)
                cs += (int)(hist[(base + j) * 2] + hist[(base + j) * 2 + 1]);
            int vv = cs;
            #pragma unroll
            for (int d = 1; d < 64; d <<= 1) {
                int o = __shfl_down(vv, d);
                if (lane + d < 64) vv += o;
            }
            if (lane == 0) wtotI[wid] = vv;
            __syncthreads();
            int off = 0;
            for (int w = wid + 1; w < 16; ++w) off += wtotI[w];
            int mine = vv + off;
            int above = mine - cs;
            if (mine >= k && above < k) {
                int run = above;
                for (int b = base + 3; b >= base; --b) {
                    int mb = (int)(hist[b * 2] + hist[b * 2 + 1]);
                    if (run + mb >= k) {
                        s_prefix = (unsigned)b; s_cntgt = run; s_total = run + mb; s_lvl = 0;
                        break;
                    }
                    run += mb;
                }
            }
        }
        for (int level = 1; level <= 2; ++level) {
            __syncthreads();
            if (s_total <= CAP) break;
            for (int i = tid; i < 512; i += NTHR) hist[i] = 0;
            __syncthreads();
            unsigned pfx = s_prefix;
            const int msh = 32 - (12 + 8 * (level - 1));
            const int bsh = msh - 8;
            for (int i = tid; i < V4; i += NTHR) {
                float4 l4 = row4[i];
                float vv4[4] = { l4.x, l4.y, l4.z, l4.w };
                #pragma unroll
                for (int j = 0; j < 4; ++j) {
                    unsigned key = keyOf(vv4[j]);
                    if ((key >> msh) == pfx)
                        atomicAdd(&hist[(((key >> bsh) & 255u) << 1) | cpy], 1u);
                }
            }
            for (int i = Vt + tid; i < V; i += NTHR) {
                unsigned key = keyOf(row[i]);
                if ((key >> msh) == pfx)
                    atomicAdd(&hist[(((key >> bsh) & 255u) << 1) | cpy], 1u);
            }
            __syncthreads();
            if (tid == 0) {
                int run = s_cntgt;
                for (int b = 255; b >= 0; --b) {
                    int mb = (int)(hist[b * 2] + hist[b * 2 + 1]);
                    if (run + mb >= k) {
                        s_prefix = (pfx << 8) | (unsigned)b; s_cntgt = run; s_total = run + mb;
                        break;
                    }
                    run += mb;
                }
                s_lvl = level;
            }
        }
        __syncthreads();
        tlo = s_prefix << (20 - 8 * s_lvl);
        thrF = valOfKey(tlo);
        if (tid == 0) s_ncand = 0;
        __syncthreads();
        {
            int i = tid;
            for (; i + 3 * NTHR < V4; i += 4 * NTHR) {
                float4 a = row4[i];
                float4 b = row4[i + NTHR];
                float4 c = row4[i + 2 * NTHR];
                float4 d = row4[i + 3 * NTHR];
                SPEC1(a.x, i * 4 + 0, thrF); SPEC1(a.y, i * 4 + 1, thrF);
                SPEC1(a.z, i * 4 + 2, thrF); SPEC1(a.w, i * 4 + 3, thrF);
                SPEC1(b.x, (i + NTHR) * 4 + 0, thrF); SPEC1(b.y, (i + NTHR) * 4 + 1, thrF);
                SPEC1(b.z, (i + NTHR) * 4 + 2, thrF); SPEC1(b.w, (i + NTHR) * 4 + 3, thrF);
                SPEC1(c.x, (i + 2 * NTHR) * 4 + 0, thrF); SPEC1(c.y, (i + 2 * NTHR) * 4 + 1, thrF);
                SPEC1(c.z, (i + 2 * NTHR) * 4 + 2, thrF); SPEC1(c.w, (i + 2 * NTHR) * 4 + 3, thrF);
                SPEC1(d.x, (i + 3 * NTHR) * 4 + 0, thrF); SPEC1(d.y, (i + 3 * NTHR) * 4 + 1, thrF);
                SPEC1(d.z, (i + 3 * NTHR) * 4 + 2, thrF); SPEC1(d.w, (i + 3 * NTHR) * 4 + 3, thrF);
            }
            for (; i < V4; i += NTHR) {
                float4 a = row4[i];
                SPEC1(a.x, i * 4 + 0, thrF); SPEC1(a.y, i * 4 + 1, thrF);
                SPEC1(a.z, i * 4 + 2, thrF); SPEC1(a.w, i * 4 + 3, thrF);
            }
            for (int ii = Vt + tid; ii < V; ii += NTHR)
                SPEC1(row[ii], ii, thrF);
        }
        __syncthreads();
        ncand = s_ncand;
        if (ncand > CAP) ncand = CAP;
        if (k > ncand) k = ncand;
    }
    if (k > ncand) k = ncand;                             // safety (fast: no-op)

    // ------- Phase 2.5: adaptive exact/near-exact refine (ncand > 1024) -------
    bool fromC2 = false;
    bool bigSort = false;
    if (ncand > SMALL) {
        unsigned pfx; int run; int bb;
        if (fastok) { pfx = 0u; run = 0; bb = 32; }       // full key unknown
        else { pfx = s_prefix; run = s_cntgt; bb = 20 - 8 * s_lvl; }
        int totR = ncand;                                 // bound on kept count
        while (totR > SMALL - 16 && bb > 0) {
            int step = (bb >= 8) ? 8 : bb;
            bb -= step;
            int nbins = 1 << step;
            for (int i = tid; i < 16 * 257; i += NTHR) refHist[i] = 0;
            __syncthreads();
            {
                const int sh = bb + step;
                const unsigned lc = (unsigned)(lane & 15) * 257u;
                for (int i = tid; i < ncand; i += NTHR) {
                    unsigned key = (unsigned)(cand[i] >> 32);
                    bool in = (sh >= 32) || ((key >> sh) == pfx);
                    if (in)
                        atomicAdd(&refHist[lc + ((key >> bb) & (unsigned)(nbins - 1))], 1u);
                }
            }
            __syncthreads();
            int cnt = 0;
            if (tid < 256 && tid < nbins) {
                #pragma unroll
                for (int c = 0; c < 16; ++c) cnt += (int)refHist[c * 257 + tid];
            }
            int vv = cnt;
            #pragma unroll
            for (int d = 1; d < 64; d <<= 1) {
                int o = __shfl_down(vv, d);
                if (lane + d < 64) vv += o;
            }
            if (tid < 256 && lane == 0) wtotI[wid] = vv;
            __syncthreads();
            if (tid < 256) {
                int off = 0;
                for (int w = wid + 1; w < 4; ++w) off += wtotI[w];
                int incl = vv + off;
                int abv = incl - cnt;
                int kk = k - run;
                if (incl >= kk && abv < kk) {             // exactly one bin
                    s_prefix = (pfx << step) | (unsigned)tid;
                    s_cntgt = run + abv;
                    s_total = run + abv + cnt;
                }
            }
            __syncthreads();
            pfx = s_prefix;
            run = s_cntgt;
            totR = s_total;
        }
        // cut at bin floor - GUARD: superset of exact-kth 16-ulp band
        unsigned tref0 = (bb > 0) ? (pfx << bb) : pfx;
        unsigned tref = (tref0 >= GUARD) ? (tref0 - GUARD) : 0u;
        if (tid == 0) s_nc2 = 0;
        __syncthreads();
        for (int i = tid; i < ncand; i += NTHR) {
            unsigned long long cv = cand[i];
            bool pred = ((unsigned)(cv >> 32) >= tref);
            unsigned long long mask = __ballot(pred ? 1 : 0);
            if (mask) {
                int leader = __ffsll(mask) - 1;
                int cnt2 = __popcll(mask);
                int bpos = 0;
                if (lane == leader) bpos = atomicAdd(&s_nc2, cnt2);
                bpos = __shfl(bpos, leader);
                if (pred) {
                    int pos = bpos + __popcll(mask & ((1ULL << lane) - 1ULL));
                    if (pos < SMALL) cand2[pos] = cv;
                }
            }
        }
        __syncthreads();
        int nc2 = s_nc2;
        if (nc2 <= SMALL) { ncand = nc2; fromC2 = true; }
        else bigSort = true;                              // pathological key ties
    }

    // ---------------- Phase 3: descending sort --------------------------------
    if (!bigSort) {
        // register/shfl hybrid bitonic, P=1024, 1 elem/thread; LDS exchanges
        // single-barrier via 2-segment ping-pong (10 passes, even count).
        const unsigned long long* src = fromC2 ? cand2 : cand;
        unsigned long long v = (tid < ncand) ? src[tid] : 0ULL;
        int seg = 0;
        #pragma unroll
        for (int size = 2; size <= SMALL; size <<= 1) {
            #pragma unroll
            for (int stride = size >> 1; stride > 0; stride >>= 1) {
                unsigned long long o;
                if (stride < 64) {
                    o = shflXor64(v, stride);             // intra-wave: no barrier
                } else {
                    cand[seg * SMALL + tid] = v;
                    __syncthreads();
                    o = cand[seg * SMALL + (tid ^ stride)];
                    seg ^= 1;
                }
                bool takeMax = (((tid & size) == 0) == ((tid & stride) == 0));
                unsigned long long mx = (v > o) ? v : o;
                unsigned long long mn = (v > o) ? o : v;
                v = takeMax ? mx : mn;
            }
        }
        // last LDS pass used seg1 -> writes to cand[0..1023] are race-free
        cand[tid] = v;
        varr[tid] = (tid < ncand) ? (valOfKey((unsigned)(v >> 32)) / t) : NEG_BIG;
        __syncthreads();
    } else {
        // fallback: LDS bitonic over up to CAP elements
        int P = 2; while (P < ncand) P <<= 1;
        for (int i = ncand + tid; i < P; i += NTHR) cand[i] = 0ULL;
        __syncthreads();
        for (int size = 2; size <= P; size <<= 1) {
            for (int stride = size >> 1; stride > 0; stride >>= 1) {
                for (int i = tid; i < P; i += NTHR) {
                    int j = i ^ stride;
                    if (j > i) {
                        unsigned long long a = cand[i], b = cand[j];
                        bool up = ((i & size) == 0);
                        bool sw = up ? (a < b) : (a > b);
                        if (sw) { cand[i] = b; cand[j] = a; }
                    }
                }
                __syncthreads();
            }
        }
        for (int i = tid; i < 1024; i += NTHR)
            varr[i] = (i < ncand) ? (valOfKey((unsigned)(cand[i] >> 32)) / t) : NEG_BIG;
        __syncthreads();
    }

    // ---------------- Phase 4: top-k/top-p/sample (numerics unchanged) --------
    const float m = varr[0];
    const float tkeyV = varr[k - 1];              // k-th largest v
    int ntop = k;                                 // expand ties at threshold
    while (ntop < ncand) {
        float vi = (ntop < 1024) ? varr[ntop]
                                 : (valOfKey((unsigned)(cand[ntop] >> 32)) / t);
        if (vi != tkeyV) break;
        ++ntop;
    }
    if (ntop > 1024) ntop = 1024;

    {
        float e = (tid < ntop) ? expf(varr[tid] - m) : 0.0f;
        Earr[tid] = e;
        sfx[tid] = e;
        if (tid == 0) { s_nkeep = 0; s_rank = 0; s_amax = 0ULL; }
        if (tid < 64) bitmap[tid] = 0;
    }
    __syncthreads();
    {
        // inclusive suffix scan, double-buffered: new[i] = old[i] + old[i+d]
        // -- identical addition order to the previous in-place 2-barrier tree.
        float* A = sfx;
        float* Bf = sfx2;
        #pragma unroll
        for (int d = 1; d < 1024; d <<= 1) {
            float t0 = (tid + d < 1024) ? A[tid + d] : 0.0f;
            Bf[tid] = A[tid] + t0;
            __syncthreads();
            float* tmp = A; A = Bf; Bf = tmp;
        }
        // 10 steps (even) -> final values land back in sfx
    }
    const float Zp = sfx[0];
    const float cmp = 1.0f - p;
    {
        int local = 0;
        for (int i = tid; i < ntop; i += NTHR)
            if (sfx[i] / Zp > cmp) local++;       // keep iff ascending-cum > 1-p
        #pragma unroll
        for (int d = 1; d < 64; d <<= 1) local += __shfl_xor(local, d);
        if (lane == 0 && local) atomicAdd(&s_nkeep, local);
    }
    __syncthreads();
    const int nkeep = s_nkeep;                    // >= 1
    if (tid == 0) {                               // boundary v-tie group
        float vb = varr[nkeep - 1];
        int g0 = nkeep - 1;
        while (g0 > 0 && varr[g0 - 1] == vb) --g0;
        int g1 = nkeep;
        while (g1 < ntop && varr[g1] == vb) ++g1;
        s_g0 = g0; s_g1 = g1;
    }
    __syncthreads();
    const int g0 = s_g0, g1 = s_g1;
    const int mkeep = nkeep - g0;
    // kept members of boundary group = mkeep HIGHEST vocab indices
    for (int i = g0 + tid; i < g1; i += NTHR) {
        unsigned gi = ~(unsigned)(cand[i] & 0xFFFFFFFFull);
        int rk = 0;
        for (int j = g0; j < g1; ++j) {
            unsigned gj = ~(unsigned)(cand[j] & 0xFFFFFFFFull);
            if (gj > gi) rk++;
        }
        flagArr[i] = (rk < mkeep) ? 1 : 0;
    }
    __syncthreads();

    const float Z2 = (nkeep < 1024) ? (Zp - sfx[nkeep]) : Zp;
    const float L = logf(Z2);

    // gumbel argmax over kept set (wave-reduced; max is order-independent)
    {
        unsigned long long lm = 0ULL;
        for (int i = tid; i < g1; i += NTHR) {
            if (i < g0 || flagArr[i]) {
                unsigned lo = (unsigned)(cand[i] & 0xFFFFFFFFull);
                unsigned gidx = ~lo;
                float u = urow[gidx];
                float q = -((u >= RMAX_F) ? RMAX_LOG_F : logf(u));
                float prob = Earr[i] / Z2;
                float ratio = greedy ? prob : (prob / q);
                unsigned long long comp = ((unsigned long long)__float_as_uint(ratio) << 32) | lo;
                if (comp > lm) lm = comp;
                if (gidx < 2048) atomicOr(&bitmap[gidx >> 5], 1u << (gidx & 31));
            }
        }
        #pragma unroll
        for (int d = 1; d < 64; d <<= 1) {
            unsigned long long o = shflXor64(lm, d);
            if (o > lm) lm = o;
        }
        if (lane == 0 && lm) atomicMax(&s_amax, lm);
    }
    __syncthreads();
    const unsigned samp_lo = (unsigned)(s_amax & 0xFFFFFFFFull);
    const unsigned samp = ~samp_lo;
    for (int i = tid; i < ntop; i += NTHR)
        if ((unsigned)(cand[i] & 0xFFFFFFFFull) == samp_lo) s_vs = varr[i];
    __syncthreads();
    const float lp_s = (s_vs - m) - L;
    {
        int local = 0;
        for (int i = tid; i < nkeep; i += NTHR)
            if ((varr[i] - m) - L > lp_s) local++;
        #pragma unroll
        for (int d = 1; d < 64; d <<= 1) local += __shfl_xor(local, d);
        if (lane == 0 && local) atomicAdd(&s_rank, local);
    }
    __syncthreads();

    // ---------------- Phase 5: outputs (parallel emission) --------------------
    // d_out (float): [B] sampled | [B,K+1] indices | [B,K+1] lp_vals | [B] ranks
    float* o_samp = out;
    float* o_idx  = out + B;
    float* o_lp   = out + B + (long long)B * (K + 1);
    float* o_rank = out + B + 2LL * B * (K + 1);
    const long long rowo = (long long)r * (K + 1);
    const int ntk = (nkeep < K) ? nkeep : K;

    // slot(i) = #kept before i's v-run + #kept in run with smaller vocab idx;
    // identical to the serial (v desc, idx asc) run walk (lax.top_k tie-break).
    if (tid < g1) {
        const int i = tid;
        bool kept = (i < g0) || flagArr[i];
        if (kept) {
            float v = varr[i];
            int rs, re, base;
            if (i >= g0) { rs = g0; re = g1; base = g0; }
            else {
                rs = i; while (rs > 0 && varr[rs - 1] == v) --rs;
                re = i + 1; while (re < g1 && varr[re] == v) ++re;
                base = rs;
            }
            if (base < ntk) {
                unsigned myidx = ~(unsigned)(cand[i] & 0xFFFFFFFFull);
                int cnt = 0;
                for (int j = rs; j < re; ++j) {
                    if (j == i) continue;
                    if (j >= g0 && !flagArr[j]) continue;
                    unsigned gj = ~(unsigned)(cand[j] & 0xFFFFFFFFull);
                    if (gj < myidx) cnt++;
                }
                int slot = base + cnt;
                if (slot < ntk) {
                    o_idx[rowo + 1 + slot] = (float)myidx;
                    o_lp[rowo + 1 + slot] = (v - m) - L;
                }
            }
        }
    }

    if (tid == 0) {
        o_samp[r] = (float)samp;
        o_idx[rowo] = (float)samp;
        o_lp[rowo] = lp_s;
        o_rank[r] = (float)s_rank;
        if (nkeep < K) {
            // fillers: smallest non-kept vocab indices, finite "-inf"
            int j = 0;
            for (int c = nkeep; c < K; ++c) {
                while (bitmap[j >> 5] & (1u << (j & 31))) ++j;
                o_idx[rowo + 1 + c] = (float)j;
                o_lp[rowo + 1 + c] = NEG_BIG;
                ++j;
            }
        }
    }
}

extern "C" void kernel_launch(void* const* d_in, const int* in_sizes, int n_in,
                              void* d_out, int out_size, void* d_ws, size_t ws_size,
                              hipStream_t stream) {
    const float* logits      = (const float*)d_in[0];
    const float* temperature = (const float*)d_in[1];
    const int*   top_k       = (const int*)d_in[2];
    const float* top_p       = (const float*)d_in[3];
    const float* gumbel      = (const float*)d_in[4];
    int B = in_sizes[1];
    int V = in_sizes[0] / B;
    int K = (out_size / B - 4) / 2;
    sampler_kernel<<<B, NTHR, 0, stream>>>(logits, temperature, top_k, top_p,
                                           gumbel, (float*)d_out, B, V, K);
}